// Round 6
// baseline (221.997 us; speedup 1.0000x reference)
//
#include <hip/hip_runtime.h>
#include <math.h>

#define G_   32
#define NPG_ 512
#define N_   16384
#define E_   262144
#define D_   256
#define H_   8
#define FF_  1024
#define BCAP 512   // per (g, qt32, key-half) bucket: avg 256, cap = 16 sigma
#define SB   264   // bias slab stride (dwords)

typedef unsigned int u32;
typedef unsigned short u16;
typedef __attribute__((ext_vector_type(8))) short s16x8;   // 8 x bf16
typedef __attribute__((ext_vector_type(4))) float f32x4;

__device__ inline u16 f2bf(float f) {
  u32 u = __float_as_uint(f);
  u += 0x7fffu + ((u >> 16) & 1u);
  return (u16)(u >> 16);
}

// ---------------------------------------------------------------- LayerNorm (bf16 out)
__global__ __launch_bounds__(256) void ln_kernel(const float* __restrict__ in,
                                                 const float* __restrict__ gw,
                                                 const float* __restrict__ bw,
                                                 u16* __restrict__ out) {
  const int wave = threadIdx.x >> 6, lane = threadIdx.x & 63;
  const int row = (blockIdx.x << 2) + wave;
  const float4 v = reinterpret_cast<const float4*>(in + (size_t)row * D_)[lane];
  float s = v.x + v.y + v.z + v.w;
#pragma unroll
  for (int off = 32; off > 0; off >>= 1) s += __shfl_xor(s, off);
  const float m = s * (1.0f / D_);
  const float dx = v.x - m, dy = v.y - m, dz = v.z - m, dw = v.w - m;
  float s2 = dx * dx + dy * dy + dz * dz + dw * dw;
#pragma unroll
  for (int off = 32; off > 0; off >>= 1) s2 += __shfl_xor(s2, off);
  const float inv = rsqrtf(s2 * (1.0f / D_) + 1e-5f);
  const float4 g4 = reinterpret_cast<const float4*>(gw)[lane];
  const float4 b4 = reinterpret_cast<const float4*>(bw)[lane];
  ushort4 o;
  o.x = f2bf(dx * inv * g4.x + b4.x);
  o.y = f2bf(dy * inv * g4.y + b4.y);
  o.z = f2bf(dz * inv * g4.z + b4.z);
  o.w = f2bf(dw * inv * g4.w + b4.w);
  *reinterpret_cast<ushort4*>(out + (size_t)row * D_ + (lane << 2)) = o;
}

// ---------------------------------------------------------------- fused weight prep
__global__ void wt_conv_all(const float* __restrict__ wq, const float* __restrict__ wk,
                            const float* __restrict__ wv, const float* __restrict__ w1,
                            const float* __restrict__ w2,
                            u16* __restrict__ wqkvt, u16* __restrict__ w1t,
                            u16* __restrict__ w2t,
                            const float* __restrict__ bq, const float* __restrict__ bk,
                            const float* __restrict__ bv, float* __restrict__ bqkv,
                            u32* __restrict__ cnt, u32* __restrict__ amask) {
  const int bid = blockIdx.x;
  const int tx = threadIdx.x, ty = threadIdx.y;
  if (bid == 704) {
    const int t = ty * 32 + tx;
    for (int i = t; i < 768; i += 256)
      bqkv[i] = (i < 256) ? bq[i] : (i < 512 ? bk[i - 256] : bv[i - 512]);
    for (int i = t; i < 1024; i += 256) cnt[i] = 0u;
    for (int i = t; i < 8192; i += 256) amask[i] = 0u;
    return;
  }
  const float* W; u16* Wt; int K, Nc, ro, local;
  if (bid < 64)       { W = wq; Wt = wqkvt; K = 256;  Nc = 256;  ro = 0;   local = bid; }
  else if (bid < 128) { W = wk; Wt = wqkvt; K = 256;  Nc = 256;  ro = 256; local = bid - 64; }
  else if (bid < 192) { W = wv; Wt = wqkvt; K = 256;  Nc = 256;  ro = 512; local = bid - 128; }
  else if (bid < 448) { W = w1; Wt = w1t;   K = 256;  Nc = 1024; ro = 0;   local = bid - 192; }
  else                { W = w2; Wt = w2t;   K = 1024; Nc = 256;  ro = 0;   local = bid - 448; }
  const int tn = Nc >> 5;
  const int n0 = (local % tn) << 5, k0 = (local / tn) << 5;
  __shared__ float tl[32][33];
#pragma unroll
  for (int i = 0; i < 4; ++i)
    tl[ty + (i << 3)][tx] = W[(size_t)(k0 + ty + (i << 3)) * Nc + n0 + tx];
  __syncthreads();
#pragma unroll
  for (int i = 0; i < 4; ++i)
    Wt[(size_t)(ro + n0 + ty + (i << 3)) * K + k0 + tx] = f2bf(tl[tx][ty + (i << 3)]);
}

// ---------------------------------------------------------------- edge prep
// gated weights for all 8 heads (bf16x8); bucket by (g, ls>>5, ld>>8) -> 1024 buckets
// + graph-0 adjacency bitmask (dedup for rel_pos term)
__global__ __launch_bounds__(256) void edge_prep(const int* __restrict__ ei,
                                                 const float* __restrict__ ea,
                                                 const float* __restrict__ wep,
                                                 const float* __restrict__ bep,
                                                 const float* __restrict__ weg,
                                                 const float* __restrict__ beg,
                                                 u32* __restrict__ cnt,
                                                 u32* __restrict__ rec_id,
                                                 uint4* __restrict__ rec_ew,
                                                 u32* __restrict__ amask) {
  const int e = blockIdx.x * 256 + threadIdx.x;
  const int ls = ei[e] & 511;
  const int ld = ei[E_ + e] & 511;
  if (e < 8192)  // graph 0: src,dst < 512 -> adjacency bit (deduped by OR)
    atomicOr(&amask[(ls << 4) + (ld >> 5)], 1u << (ld & 31));
  const int bk = ((e >> 13) << 5) | ((ls >> 5) << 1) | (ld >> 8);
  const u32 pos = atomicAdd(&cnt[bk], 1u);
  if (pos < (u32)BCAP) {
    const float2 a2 = reinterpret_cast<const float2*>(ea)[e];
    u32 wds[4];
#pragma unroll
    for (int hp = 0; hp < 4; ++hp) {
      u32 wd = 0;
#pragma unroll
      for (int s = 0; s < 2; ++s) {
        const int h = hp * 2 + s;
        const float pre = a2.x * wep[h] + a2.y * wep[H_ + h] + bep[h];
        const float gat = a2.x * weg[h] + a2.y * weg[H_ + h] + beg[h];
        const float ew = pre / (1.0f + __expf(-gat));
        wd |= ((u32)f2bf(ew)) << (s * 16);
      }
      wds[hp] = wd;
    }
    rec_id[bk * BCAP + pos] = (u32)((ls & 31) | ((ld & 255) << 5));
    rec_ew[(size_t)bk * BCAP + pos] = make_uint4(wds[0], wds[1], wds[2], wds[3]);
  }
}

// ---------------------------------------------------------------- MFMA GEMM (unchanged)
template <int ACT, int OUTM>
__global__ __launch_bounds__(256) void mgemm(const u16* __restrict__ A,
                                             const u16* __restrict__ Bt,
                                             const float* __restrict__ bias,
                                             const float* __restrict__ res,
                                             float* __restrict__ Cf,
                                             u16* __restrict__ Cb,
                                             u16* __restrict__ Vt,
                                             int K, int Nc) {
  __shared__ u16 s_all[17408];
  u16* sA = s_all;
  u16* sB = s_all + 8192;
  const int t = threadIdx.x;
  const int row0 = blockIdx.x << 7;
  const int col0 = blockIdx.y << 7;
  const int lane = t & 63, w = t >> 6;
  const int ql = lane & 15, u = lane >> 4;
  const int wr = w >> 1, wc = w & 1;

  f32x4 acc[4][4];
#pragma unroll
  for (int i = 0; i < 4; ++i)
#pragma unroll
    for (int j = 0; j < 4; ++j) acc[i][j] = (f32x4){0.f, 0.f, 0.f, 0.f};

  const u16* Ab = A + (size_t)row0 * K;
  const u16* Bb = Bt + (size_t)col0 * K;

  for (int k0 = 0; k0 < K; k0 += 64) {
    __syncthreads();
#pragma unroll
    for (int it = 0; it < 4; ++it) {
      const int idx = (it << 8) + t;
      const int row = idx >> 3, gc = idx & 7;
      const int sw = ((gc ^ (row & 7)) << 3);
      *reinterpret_cast<s16x8*>(sA + row * 64 + sw) =
          *reinterpret_cast<const s16x8*>(Ab + (size_t)row * K + k0 + (gc << 3));
    }
#pragma unroll
    for (int it = 0; it < 4; ++it) {
      const int idx = (it << 8) + t;
      const int row = idx >> 3, gc = idx & 7;
      const int sw = ((gc ^ (row & 7)) << 3);
      *reinterpret_cast<s16x8*>(sB + row * 64 + sw) =
          *reinterpret_cast<const s16x8*>(Bb + (size_t)row * K + k0 + (gc << 3));
    }
    __syncthreads();
#pragma unroll
    for (int ks = 0; ks < 2; ++ks) {
      const int gk = (ks << 2) + u;
      s16x8 aF[4], bF[4];
#pragma unroll
      for (int i = 0; i < 4; ++i) {
        const int ra = (wr << 6) + (i << 4) + ql;
        aF[i] = *reinterpret_cast<const s16x8*>(sA + ra * 64 + ((gk ^ (ra & 7)) << 3));
        const int rb = (wc << 6) + (i << 4) + ql;
        bF[i] = *reinterpret_cast<const s16x8*>(sB + rb * 64 + ((gk ^ (rb & 7)) << 3));
      }
#pragma unroll
      for (int i = 0; i < 4; ++i)
#pragma unroll
        for (int j = 0; j < 4; ++j)
          acc[i][j] = __builtin_amdgcn_mfma_f32_16x16x32_bf16(aF[i], bF[j], acc[i][j], 0, 0, 0);
    }
  }

  float b_[4];
#pragma unroll
  for (int j = 0; j < 4; ++j) b_[j] = bias[col0 + (wc << 6) + (j << 4) + ql];

  if (OUTM == 1) {
#pragma unroll
    for (int i = 0; i < 4; ++i)
#pragma unroll
      for (int j = 0; j < 4; ++j)
#pragma unroll
        for (int r = 0; r < 4; ++r) {
          const int row = row0 + (wr << 6) + (i << 4) + (u << 2) + r;
          const int col = col0 + (wc << 6) + (j << 4) + ql;
          Cf[(size_t)row * Nc + col] = acc[i][j][r] + b_[j] + res[(size_t)row * Nc + col];
        }
    return;
  }

  bool rowmajor = (OUTM == 0);
  if (OUTM == 2) {
    if (col0 < 512) rowmajor = true;
    else {
      const int g = row0 >> 9;
      const int key0 = (row0 & 511) + (wr << 6);
#pragma unroll
      for (int i = 0; i < 4; ++i)
#pragma unroll
        for (int j = 0; j < 4; ++j) {
          const int c = (col0 - 512) + (wc << 6) + (j << 4) + ql;
          const int hh = c >> 5, d = c & 31;
          ushort4 pk;
          pk.x = f2bf(acc[i][j][0] + b_[j]);
          pk.y = f2bf(acc[i][j][1] + b_[j]);
          pk.z = f2bf(acc[i][j][2] + b_[j]);
          pk.w = f2bf(acc[i][j][3] + b_[j]);
          *reinterpret_cast<ushort4*>(Vt + ((((size_t)g << 3) + hh) << 14) + d * 512 +
                                      key0 + (i << 4) + (u << 2)) = pk;
        }
      return;
    }
  }

  if (rowmajor) {
    __syncthreads();
    u16* sC = s_all;  // [128][136]
#pragma unroll
    for (int i = 0; i < 4; ++i)
#pragma unroll
      for (int j = 0; j < 4; ++j)
#pragma unroll
        for (int r = 0; r < 4; ++r) {
          float v = acc[i][j][r] + b_[j];
          if (ACT) v = fmaxf(v, 0.f);
          const int row = (wr << 6) + (i << 4) + (u << 2) + r;
          const int col = (wc << 6) + (j << 4) + ql;
          sC[row * 136 + col] = f2bf(v);
        }
    __syncthreads();
    const int ncb = (OUTM == 2) ? 512 : Nc;
#pragma unroll
    for (int it = 0; it < 8; ++it) {
      const int idx = (it << 8) + t;
      const int row = idx >> 4, gc = idx & 15;
      *reinterpret_cast<s16x8*>(Cb + (size_t)(row0 + row) * ncb + col0 + (gc << 3)) =
          *reinterpret_cast<const s16x8*>(sC + row * 136 + (gc << 3));
    }
  }
}

// ---------------------------------------------------------------- Attention v6
// WG = (g, h, qt32); 512 threads = 8 waves. Two-pass key halves over a
// TRANSPOSED bias slab [32 q][264 key] f32 (b128 apply reads; apply(0) rezeros).
// LDS dwords: bias 8448 (P[32][512]bf16 aliases [0,8192)) | ot[32][36]=1152
//             | statM 256 | statS 256 = 10112 dwords = 40448 B -> 4 WG/CU.
__global__ __launch_bounds__(512, 4) void attn_kernel(
    const u16* __restrict__ qk, const u16* __restrict__ vt,
    const u32* __restrict__ rec_id, const u32* __restrict__ rec_ew32,
    const u32* __restrict__ cnt, const u32* __restrict__ amask,
    const float* __restrict__ relpos,
    const float* __restrict__ x, float* __restrict__ x1) {
  extern __shared__ u32 smem_u[];
  float* s_bias  = (float*)smem_u;              // [32][264] f32
  u16*   s_p     = (u16*)smem_u;                // [32][512] bf16 (alias)
  float* s_ot    = (float*)(smem_u + 8448);     // [32][36] f32
  float* s_statM = (float*)(smem_u + 9600);     // [2][16][8]
  float* s_statS = (float*)(smem_u + 9856);     // [2][16][8]

  const int braw = blockIdx.x;
  const int b = ((braw & 7) << 9) + (braw >> 3);  // XCD swizzle (4096 % 8 == 0)
  const int qt = b & 15, h = (b >> 4) & 7, g = b >> 7;
  const int t = threadIdx.x;
  const int n0 = (g << 9) + (qt << 5);
  const int lane = t & 63, w = t >> 6;  // w in 0..7
  const int ql = lane & 15, u = lane >> 4;
  const float scale = 0.17677669529663687f;  // 1/sqrt(32)
  const float rpv = relpos[h];

  // ---- prefetch Q (2) + K (2x2) fragments
  s16x8 qf8[2], kf8[2][2];
#pragma unroll
  for (int qf = 0; qf < 2; ++qf)
    qf8[qf] = *reinterpret_cast<const s16x8*>(
        qk + (size_t)(n0 + (qf << 4) + ql) * 512 + (h << 5) + (u << 3));
#pragma unroll
  for (int half = 0; half < 2; ++half)
#pragma unroll
    for (int kf2 = 0; kf2 < 2; ++kf2)
      kf8[half][kf2] = *reinterpret_cast<const s16x8*>(
          qk + (size_t)((g << 9) + (half << 8) + (w << 5) + (kf2 << 4) + ql) * 512 + 256 +
          (h << 5) + (u << 3));

  {  // zero bias + ot (dwords [0, 9600))
    f32x4* z = (f32x4*)smem_u;
    const f32x4 zv = {0.f, 0.f, 0.f, 0.f};
    for (int i = t; i < 2400; i += 512) z[i] = zv;
  }

  // ---- QK^T (swapped): S^T[key][q]; 8 MFMAs, register-only
  f32x4 acc[2][2][2];
#pragma unroll
  for (int half = 0; half < 2; ++half)
#pragma unroll
    for (int kf2 = 0; kf2 < 2; ++kf2)
#pragma unroll
      for (int qf = 0; qf < 2; ++qf) {
        acc[half][kf2][qf] = (f32x4){0.f, 0.f, 0.f, 0.f};
        acc[half][kf2][qf] = __builtin_amdgcn_mfma_f32_16x16x32_bf16(
            kf8[half][kf2], qf8[qf], acc[half][kf2][qf], 0, 0, 0);
      }
  __syncthreads();  // zero done

  float mx[2] = {-1e30f, -1e30f};

#pragma unroll
  for (int half = 0; half < 2; ++half) {
    {  // scatter this half's records
      const int bkt = (g << 5) | (qt << 1) | half;
      const u32 cn = cnt[bkt];
      const int n = cn > (u32)BCAP ? BCAP : (int)cn;
      const u32* ridb = rec_id + bkt * BCAP;
      const u32* rewb = rec_ew32 + ((size_t)bkt * BCAP) * 4 + (h >> 1);
      for (int i = t; i < n; i += 512) {
        const u32 id = ridb[i];
        const u32 wrd = rewb[(size_t)i << 2];
        const u32 bits = (h & 1) ? (wrd & 0xffff0000u) : (wrd << 16);
        atomicAdd(&s_bias[(id & 31) * SB + (id >> 5)], __uint_as_float(bits));
      }
    }
    __syncthreads();  // scatter done
    if (g == 0) {     // fold rel_pos * A into bias slab (deduped via global bitmask)
      if (t < 256) {
        const int qrow = t >> 3, w8 = t & 7;
        u32 m = amask[(((qt << 5) + qrow) << 4) + (half << 3) + w8];
        float* row = s_bias + qrow * SB + (w8 << 5);
        while (m) { const int bit = __ffs(m) - 1; m &= m - 1; row[bit] += rpv; }
      }
      __syncthreads();
    }
    // apply bias (b128 reads) + rezero on half 0; track row max
#pragma unroll
    for (int kf2 = 0; kf2 < 2; ++kf2) {
      const int kb = (w << 5) + (kf2 << 4) + (u << 2);
#pragma unroll
      for (int qf = 0; qf < 2; ++qf) {
        const int q = (qf << 4) + ql;
        const f32x4 bz = *reinterpret_cast<const f32x4*>(s_bias + q * SB + kb);
        if (half == 0)
          *reinterpret_cast<f32x4*>(s_bias + q * SB + kb) = (f32x4){0.f, 0.f, 0.f, 0.f};
#pragma unroll
        for (int r = 0; r < 4; ++r) {
          const float v = fmaf(acc[half][kf2][qf][r], scale, bz[r]);
          acc[half][kf2][qf][r] = v;
          mx[qf] = fmaxf(mx[qf], v);
        }
      }
    }
    if (half == 0) __syncthreads();  // rezero visible before scatter(1)
  }

  // ---- cross-wave row max
#pragma unroll
  for (int qf = 0; qf < 2; ++qf) {
    mx[qf] = fmaxf(mx[qf], __shfl_xor(mx[qf], 16));
    mx[qf] = fmaxf(mx[qf], __shfl_xor(mx[qf], 32));
  }
  if (lane < 16) {
    s_statM[(ql << 3) + w] = mx[0];
    s_statM[128 + (ql << 3) + w] = mx[1];
  }
  __syncthreads();  // apply(1) bias reads done; statM visible; P region writable

  {  // ---- exp + P (bf16, swizzled) + sums
    float M[2], sum[2] = {0.f, 0.f};
#pragma unroll
    for (int qf = 0; qf < 2; ++qf) {
      const float* sm = s_statM + (qf << 7) + (ql << 3);
      const f32x4 a = *reinterpret_cast<const f32x4*>(sm);
      const f32x4 c = *reinterpret_cast<const f32x4*>(sm + 4);
      M[qf] = fmaxf(fmaxf(fmaxf(a[0], a[1]), fmaxf(a[2], a[3])),
                    fmaxf(fmaxf(c[0], c[1]), fmaxf(c[2], c[3])));
    }
#pragma unroll
    for (int half = 0; half < 2; ++half)
#pragma unroll
      for (int kf2 = 0; kf2 < 2; ++kf2) {
        const int kl0 = (half << 8) + (w << 5) + (kf2 << 4) + (u << 2);
        const int gran = kl0 >> 3;
#pragma unroll
        for (int qf = 0; qf < 2; ++qf) {
          const int q = (qf << 4) + ql;
          float e[4];
#pragma unroll
          for (int r = 0; r < 4; ++r) {
            e[r] = __expf(acc[half][kf2][qf][r] - M[qf]);
            sum[qf] += e[r];
          }
          uint2 pw;
          pw.x = (u32)f2bf(e[0]) | ((u32)f2bf(e[1]) << 16);
          pw.y = (u32)f2bf(e[2]) | ((u32)f2bf(e[3]) << 16);
          *reinterpret_cast<uint2*>(s_p + (q << 9) + ((gran ^ (q & 7)) << 3) + (kl0 & 7)) = pw;
        }
      }
#pragma unroll
    for (int qf = 0; qf < 2; ++qf) {
      sum[qf] += __shfl_xor(sum[qf], 16);
      sum[qf] += __shfl_xor(sum[qf], 32);
    }
    if (lane < 16) {
      s_statS[(ql << 3) + w] = sum[0];
      s_statS[128 + (ql << 3) + w] = sum[1];
    }
  }
  __syncthreads();  // P + sums visible

  {  // ---- PV: wave role (kh = w>>2 key-half, wd = dim-frag, wq = q-frag); dual chains
    const int wq = w & 1, wd = (w >> 1) & 1, kh = w >> 2;
    const u16* vtb = vt + ((((size_t)g << 3) + h) << 14) +
                     (size_t)((wd << 4) + ql) * 512 + (kh << 8);
    const int q = (wq << 4) + ql;
    f32x4 o0 = (f32x4){0.f, 0.f, 0.f, 0.f}, o1 = (f32x4){0.f, 0.f, 0.f, 0.f};
#pragma unroll
    for (int ks = 0; ks < 8; ks += 2) {
      const int k0 = (kh << 8) + (ks << 5) + (u << 3);
      const s16x8 va0 = *reinterpret_cast<const s16x8*>(vtb + (ks << 5) + (u << 3));
      const s16x8 pb0 = *reinterpret_cast<const s16x8*>(
          s_p + (q << 9) + (((k0 >> 3) ^ (q & 7)) << 3));
      o0 = __builtin_amdgcn_mfma_f32_16x16x32_bf16(va0, pb0, o0, 0, 0, 0);
      const int k1 = k0 + 32;
      const s16x8 va1 = *reinterpret_cast<const s16x8*>(vtb + ((ks + 1) << 5) + (u << 3));
      const s16x8 pb1 = *reinterpret_cast<const s16x8*>(
          s_p + (q << 9) + (((k1 >> 3) ^ (q & 7)) << 3));
      o1 = __builtin_amdgcn_mfma_f32_16x16x32_bf16(va1, pb1, o1, 0, 0, 0);
    }
#pragma unroll
    for (int r = 0; r < 4; ++r)
      atomicAdd(&s_ot[q * 36 + (wd << 4) + (u << 2) + r], o0[r] + o1[r]);
  }
  __syncthreads();

  if (t < 256) {  // ---- epilogue: 1/S scale + x residual
    const int q = t >> 3, d4 = (t & 7) << 2;
    const float* ss = s_statS + ((q >> 4) << 7) + ((q & 15) << 3);
    const f32x4 sa = *reinterpret_cast<const f32x4*>(ss);
    const f32x4 sb = *reinterpret_cast<const f32x4*>(ss + 4);
    const float invS = 1.0f / (sa[0] + sa[1] + sa[2] + sa[3] + sb[0] + sb[1] + sb[2] + sb[3]);
    const f32x4 ov = *reinterpret_cast<const f32x4*>(s_ot + q * 36 + d4);
    const size_t oi = (size_t)(n0 + q) * D_ + (h << 5) + d4;
    const f32x4 xv = *reinterpret_cast<const f32x4*>(x + oi);
    f32x4 o;
#pragma unroll
    for (int j = 0; j < 4; ++j) o[j] = ov[j] * invS + xv[j];
    *reinterpret_cast<f32x4*>(x1 + oi) = o;
  }
}

// ---------------------------------------------------------------- launch
extern "C" void kernel_launch(void* const* d_in, const int* in_sizes, int n_in,
                              void* d_out, int out_size, void* d_ws, size_t ws_size,
                              hipStream_t stream) {
  const float* x    = (const float*)d_in[0];
  const int*   ei   = (const int*)d_in[1];
  const float* ea   = (const float*)d_in[2];
  const float* ln1g = (const float*)d_in[3];
  const float* ln1b = (const float*)d_in[4];
  const float* wq   = (const float*)d_in[5];
  const float* bq   = (const float*)d_in[6];
  const float* wk   = (const float*)d_in[7];
  const float* bk   = (const float*)d_in[8];
  const float* wv   = (const float*)d_in[9];
  const float* bv   = (const float*)d_in[10];
  const float* wep  = (const float*)d_in[11];
  const float* bep  = (const float*)d_in[12];
  const float* weg  = (const float*)d_in[13];
  const float* beg  = (const float*)d_in[14];
  const float* rp   = (const float*)d_in[15];
  const float* w1   = (const float*)d_in[16];
  const float* b1   = (const float*)d_in[17];
  const float* w2   = (const float*)d_in[18];
  const float* b2   = (const float*)d_in[19];
  const float* ln2g = (const float*)d_in[20];
  const float* ln2b = (const float*)d_in[21];
  float* out = (float*)d_out;

  float* ws = (float*)d_ws;
  const size_t M1 = 1048576;
  u16* xn   = (u16*)ws;                       // [16384][256] bf16
  u16* qk   = (u16*)(ws + 2 * M1);            // [16384][512] bf16 (Q|K)
  u16* vt   = (u16*)(ws + 6 * M1);            // [256][32][512] bf16
  u16* f1   = (u16*)ws;                       // [16384][1024] bf16 (alias, post-attn)
  float* x1 = ws + 8 * M1;                    // f32
  u16* h2   = (u16*)(ws + 12 * M1);           // bf16
  u16* wqkvt = (u16*)(ws + 14 * M1);          // [768][256] bf16
  u16* w1t  = (u16*)(ws + 14 * M1 + 262144);  // [1024][256] bf16
  u16* w2t  = (u16*)(ws + 14 * M1 + 524288);  // [256][1024] bf16
  float* bqkv = ws + 14 * M1 + 786432;        // [768] f32
  u32* cnt  = (u32*)(ws + 14 * M1 + 787456);  // [1024] u32
  u32* amask = (u32*)(ws + 14 * M1 + 788480); // [512][16] u32 (32KB)
  u32* rec_id = (u32*)(ws + 15 * M1);         // [1024*512] u32 (2MB)
  uint4* rec_ew = (uint4*)(ws + 16 * M1);     // [1024*512] uint4 (8MB)

  // 0. fused weight prep (packs bqkv, zeros cnt + amask), then edge prep
  wt_conv_all<<<dim3(705), dim3(32, 8), 0, stream>>>(wq, wk, wv, w1, w2, wqkvt, w1t, w2t,
                                                     bq, bk, bv, bqkv, cnt, amask);
  edge_prep<<<dim3(E_ / 256), dim3(256), 0, stream>>>(ei, ea, wep, bep, weg, beg,
                                                      cnt, rec_id, rec_ew, amask);
  // 1. LN1 -> bf16
  ln_kernel<<<dim3(N_ / 4), dim3(256), 0, stream>>>(x, ln1g, ln1b, xn);
  // 2. fused QKV GEMM: Q,K -> qk row-major; V -> vt transposed
  mgemm<0, 2><<<dim3(128, 6), 256, 0, stream>>>(xn, wqkvt, bqkv, nullptr, nullptr, qk, vt, 256, 768);
  // 3. attention (+x residual) -> x1 f32
  const int smem_attn = 10112 * 4;  // 40,448 B -> 4 WG/CU
  (void)hipFuncSetAttribute(reinterpret_cast<const void*>(attn_kernel),
                            hipFuncAttributeMaxDynamicSharedMemorySize, smem_attn);
  attn_kernel<<<dim3(G_ * H_ * 16), 512, smem_attn, stream>>>(
      qk, vt, rec_id, (const u32*)rec_ew, cnt, amask, rp, x, x1);
  // 4. LN2 -> bf16
  ln_kernel<<<dim3(N_ / 4), dim3(256), 0, stream>>>(x1, ln2g, ln2b, h2);
  // 5. FF1 (relu) -> f1 bf16
  mgemm<1, 0><<<dim3(128, 8), 256, 0, stream>>>(h2, w1t, b1, nullptr, nullptr, f1, nullptr, 256, 1024);
  // 6. FF2 (+bias +x1 residual) -> out f32
  mgemm<0, 1><<<dim3(128, 2), 256, 0, stream>>>(f1, w2t, b2, x1, out, nullptr, nullptr, 1024, 256);
}